// Round 4
// baseline (508.892 us; speedup 1.0000x reference)
//
#include <hip/hip_runtime.h>

// SelfAttnBlock: BN -> QKV 1x1conv -> full 4096x4096 attention (flash-style,
// never materialized) -> 1x1 conv -> residual.  MI355X gfx950.
//
// R4 design notes (counter-driven):
//  - R2/R3 both pinned at Occupancy 22% (2 blocks/CU) regardless of grid ->
//    static cap = unified VGPR+AGPR footprint (~180 live regs -> 256 quantum).
//  - Restructure: each wave owns 32 q-rows x ALL keys of its split; P is
//    redistributed through a PRIVATE per-wave LDS region (same-wave
//    ds_write->ds_read) -> NO barrier in the K-loop; only a bare s_barrier
//    rendezvous to keep the block's 4 waves L1-aligned on shared K/V.
//  - Register diet: Q 32 + acc 32 + sc 16 + K 16 transient + misc ~= 120;
//    __launch_bounds__(256,4) forces <=128 regs -> 4 blocks/CU.
//  - VALU diet: v_cvt_pk_bf16_f32 (RNE, same numerics) replaces manual pack.
//  - Numerics identical to R3: QK bf16 hi/lo (6 MFMAs), P/V single bf16,
//    no-max softmax in exp2 domain, split-K=4 partials via f32 atomics.

#define HW 4096
#define CC 64
#define NBATCH 8
#define SPLIT 4
#define TSTEPS 16  // 64-key steps per block (1024 keys / block)
// 0.125 * log2(e): fold attention scale + exp->exp2 conversion into Q
#define QSCALE 0.18033688011112042f

using f32x4 = __attribute__((ext_vector_type(4))) float;
using bf16x8 = __attribute__((ext_vector_type(8))) short;
using u32x2 = __attribute__((ext_vector_type(2))) unsigned int;
typedef unsigned short u16;
typedef unsigned int u32;

#if __has_builtin(__builtin_amdgcn_exp2f)
#define EXP2F(v) __builtin_amdgcn_exp2f(v)
#else
#define EXP2F(v) exp2f(v)
#endif

__device__ __forceinline__ u16 f2bf(float v) {  // RNE f32->bf16
  u32 u = __float_as_uint(v);
  return (u16)((u + 0x7fffu + ((u >> 16) & 1u)) >> 16);
}
__device__ __forceinline__ float bf2f(u16 h) {
  return __uint_as_float(((u32)h) << 16);
}
__device__ __forceinline__ u32 cvtpk_bf16(float lo, float hi) {  // RNE pack
  u32 r;
  asm("v_cvt_pk_bf16_f32 %0, %1, %2" : "=v"(r) : "v"(lo), "v"(hi));
  return r;
}

// ---------- kernel 1: BN partial sums (per (n,c) plane) -> atomics into SACC
__global__ __launch_bounds__(256) void k_stats1(const float* __restrict__ x,
                                                float* __restrict__ SACC) {
  const int n = blockIdx.x >> 6;
  const int c = blockIdx.x & 63;
  const int tid = threadIdx.x;
  const float* xp = x + ((size_t)n * CC + c) * HW;
  float s1 = 0.f, s2 = 0.f;
#pragma unroll
  for (int i = tid; i < HW; i += 256) {
    const float v = xp[i];
    s1 += v;
    s2 += v * v;
  }
#pragma unroll
  for (int m = 1; m <= 32; m <<= 1) {
    s1 += __shfl_xor(s1, m);
    s2 += __shfl_xor(s2, m);
  }
  __shared__ float r1[4], r2[4];
  const int w = tid >> 6;
  if ((tid & 63) == 0) { r1[w] = s1; r2[w] = s2; }
  __syncthreads();
  if (tid == 0) {
    unsafeAtomicAdd(SACC + c, r1[0] + r1[1] + r1[2] + r1[3]);
    unsafeAtomicAdd(SACC + CC + c, r2[0] + r2[1] + r2[2] + r2[3]);
  }
}

// ---------- kernel 2: fused BN-apply + Q/K/V 1x1 convs + bf16 hi/lo quantize
// outputs: QH/QL/KH/KL as [n][hw][c] bf16 ; V as [n][c][hw] bf16
__device__ __forceinline__ void mm16(const float* __restrict__ W,
                                     const float* __restrict__ B,
                                     const float* xcol, int o0, float scale,
                                     float* outv) {
#pragma unroll
  for (int oo = 0; oo < 16; ++oo) {
    const int o = o0 + oo;
    float a = B[o];                  // uniform per wave -> SGPR
#pragma unroll
    for (int c = 0; c < CC; ++c) a = fmaf(W[o * CC + c], xcol[c], a);
    outv[oo] = a * scale;
  }
}

__device__ __forceinline__ void split_store16(const float* v16, u16* dh, u16* dl) {
  u32 hi[8], lo[8];
#pragma unroll
  for (int e = 0; e < 8; ++e) {
    const u16 h0 = f2bf(v16[2 * e]), h1 = f2bf(v16[2 * e + 1]);
    const float l0 = v16[2 * e] - bf2f(h0);
    const float l1 = v16[2 * e + 1] - bf2f(h1);
    hi[e] = (u32)h0 | ((u32)h1 << 16);
    lo[e] = (u32)f2bf(l0) | ((u32)f2bf(l1) << 16);
  }
  ((uint4*)dh)[0] = *(const uint4*)&hi[0];
  ((uint4*)dh)[1] = *(const uint4*)&hi[4];
  ((uint4*)dl)[0] = *(const uint4*)&lo[0];
  ((uint4*)dl)[1] = *(const uint4*)&lo[4];
}

__global__ __launch_bounds__(256) void k_qkv(
    const float* __restrict__ x, const float* __restrict__ SACC,
    const float* __restrict__ gamma, const float* __restrict__ beta,
    const float* __restrict__ wq, const float* __restrict__ bq,
    const float* __restrict__ wk, const float* __restrict__ bk,
    const float* __restrict__ wv, const float* __restrict__ bv,
    u16* __restrict__ QH, u16* __restrict__ QL, u16* __restrict__ KH,
    u16* __restrict__ KL, u16* __restrict__ V) {
  const int n = blockIdx.x >> 6;
  const int i0 = (blockIdx.x & 63) << 6;
  __shared__ float xn[CC][64];
  __shared__ float sa[CC], sb[CC];
  const int tid = threadIdx.x;
  if (tid < CC) {  // BN a,b from accumulated stats (biased var, eps=1e-5)
    const float inv = 1.0f / (float)(NBATCH * HW);
    const float mean = SACC[tid] * inv;
    const float var = SACC[CC + tid] * inv - mean * mean;
    const float a = rsqrtf(var + 1e-5f) * gamma[tid];
    sa[tid] = a;
    sb[tid] = beta[tid] - mean * a;
  }
  __syncthreads();
  {
    const int p = tid & 63;
    const int c0 = (tid >> 6) << 4;
    const float* xp = x + (size_t)n * CC * HW + i0 + p;
#pragma unroll
    for (int cc = 0; cc < 16; ++cc) {
      const int c = c0 + cc;
      xn[c][p] = fmaf(xp[(size_t)c * HW], sa[c], sb[c]);
    }
  }
  __syncthreads();
  const int w = tid >> 6;  // wave -> output-channel block (uniform W reads)
  const int p = tid & 63;
  float xcol[CC];
#pragma unroll
  for (int c = 0; c < CC; ++c) xcol[c] = xn[c][p];

  const size_t row = (size_t)n * HW + i0 + p;
  float v16[16];
  mm16(wq, bq, xcol, w * 16, QSCALE, v16);
  split_store16(v16, QH + row * CC + w * 16, QL + row * CC + w * 16);
  mm16(wk, bk, xcol, w * 16, 1.0f, v16);
  split_store16(v16, KH + row * CC + w * 16, KL + row * CC + w * 16);
  mm16(wv, bv, xcol, w * 16, 1.0f, v16);
#pragma unroll
  for (int oo = 0; oo < 16; ++oo)
    V[((size_t)n * CC + w * 16 + oo) * HW + i0 + p] = f2bf(v16[oo]);
}

// ---------- kernel 3: flash attention partial; wave-independent.
// Each wave: 32 q-rows x 1024 keys. No barriers in the loop (private P LDS).
__global__ __launch_bounds__(256, 4) void k_attn(
    const u16* __restrict__ QH, const u16* __restrict__ QL,
    const u16* __restrict__ KH, const u16* __restrict__ KL,
    const u16* __restrict__ V, float* __restrict__ RES,
    float* __restrict__ Z) {
  // grid 1024 = n(8) x qtile(32) x split(4); bid&7==n -> one batch per XCD
  // (per-batch K/V ~2.5MB < 4MB XCD-L2)
  const int bid = blockIdx.x;
  const int n = bid & 7;
  const int qt = (bid >> 3) & 31;
  const int s = bid >> 8;
  const int tid = threadIdx.x;
  const int w = tid >> 6;
  const int l = tid & 63;
  const int l15 = l & 15;
  const int lg = l >> 4;
  const int qw0 = qt * 128 + w * 32;  // this wave's first q-row
  const int key0 = s * (TSTEPS * 64);

  __shared__ alignas(16) u16 P[4][32][64];  // per-wave private region
  char* const Pw = (char*)&P[w][0][0];
  const int swzW = (l15 & 7) << 4;  // byte-XOR within a 128B row

  // resident Q frags: lane holds Q[qw0+qb*16+l15][m*32+lg*8 .. +8] (hi/lo)
  bf16x8 qh[2][2], ql[2][2];
  {
    const size_t qbase = ((size_t)n * HW + qw0 + l15) * CC + lg * 8;
#pragma unroll
    for (int qb = 0; qb < 2; ++qb)
#pragma unroll
      for (int m = 0; m < 2; ++m) {
        const size_t off = qbase + (size_t)qb * 16 * CC + m * 32;
        qh[qb][m] = *(const bf16x8*)(QH + off);
        ql[qb][m] = *(const bf16x8*)(QL + off);
      }
  }

  f32x4 acc[2][4];
#pragma unroll
  for (int qb = 0; qb < 2; ++qb)
#pragma unroll
    for (int chb = 0; chb < 4; ++chb) acc[qb][chb] = (f32x4){0.f, 0.f, 0.f, 0.f};
  float zacc[2] = {0.f, 0.f};

  // A-frag K base: lane (l15,lg) reads K[key + kb*16 + l15][m*32 + lg*8 ..]
  const u16* khp = KH + ((size_t)n * HW + key0 + l15) * CC + lg * 8;
  const u16* klp = KL + ((size_t)n * HW + key0 + l15) * CC + lg * 8;
  // B-frag V base: lane reads V[chb*16+l15][key + m2*32 + lg*8 ..]
  const u16* vp = V + ((size_t)n * CC + l15) * HW + key0 + lg * 8;

#pragma unroll 1
  for (int t = 0; t < TSTEPS; ++t) {
    // ---- QK phase: per qb, scores for all 64 keys of this step
#pragma unroll
    for (int qb = 0; qb < 2; ++qb) {
      f32x4 sc[4];
#pragma unroll
      for (int kb = 0; kb < 4; ++kb) {
        const u16* kh_t = khp + (size_t)kb * 16 * CC;
        const u16* kl_t = klp + (size_t)kb * 16 * CC;
        const bf16x8 kh0 = *(const bf16x8*)(kh_t);
        const bf16x8 kh1 = *(const bf16x8*)(kh_t + 32);
        const bf16x8 kl0 = *(const bf16x8*)(kl_t);
        const bf16x8 kl1 = *(const bf16x8*)(kl_t + 32);
        f32x4 s4 = {0.f, 0.f, 0.f, 0.f};
        __builtin_amdgcn_s_setprio(1);
        s4 = __builtin_amdgcn_mfma_f32_16x16x32_bf16(kh0, qh[qb][0], s4, 0, 0, 0);
        s4 = __builtin_amdgcn_mfma_f32_16x16x32_bf16(kh1, qh[qb][1], s4, 0, 0, 0);
        s4 = __builtin_amdgcn_mfma_f32_16x16x32_bf16(kh0, ql[qb][0], s4, 0, 0, 0);
        s4 = __builtin_amdgcn_mfma_f32_16x16x32_bf16(kh1, ql[qb][1], s4, 0, 0, 0);
        s4 = __builtin_amdgcn_mfma_f32_16x16x32_bf16(kl0, qh[qb][0], s4, 0, 0, 0);
        s4 = __builtin_amdgcn_mfma_f32_16x16x32_bf16(kl1, qh[qb][1], s4, 0, 0, 0);
        __builtin_amdgcn_s_setprio(0);
        sc[kb] = s4;
      }
      // exp2 -> z -> bf16 pack -> private-LDS write (swizzled, b64)
      float zs = 0.f;
      char* const prow = Pw + (qb * 16 + l15) * 128;
#pragma unroll
      for (int kb = 0; kb < 4; ++kb) {
        const float p0 = EXP2F(sc[kb][0]);
        const float p1 = EXP2F(sc[kb][1]);
        const float p2 = EXP2F(sc[kb][2]);
        const float p3 = EXP2F(sc[kb][3]);
        zs += (p0 + p1) + (p2 + p3);
        const u32x2 pk = {cvtpk_bf16(p0, p1), cvtpk_bf16(p2, p3)};
        *(u32x2*)(prow + ((kb * 32 + lg * 8) ^ swzW)) = pk;
      }
      zacc[qb] += zs;
    }
    // ---- PV phase (same wave read-back; compiler orders LDS w->r)
#pragma unroll
    for (int m2 = 0; m2 < 2; ++m2) {
      bf16x8 vb[4];
#pragma unroll
      for (int chb = 0; chb < 4; ++chb)
        vb[chb] = *(const bf16x8*)(vp + (size_t)chb * 16 * HW + m2 * 32);
#pragma unroll
      for (int qb = 0; qb < 2; ++qb) {
        const bf16x8 pa = *(const bf16x8*)(
            Pw + (qb * 16 + l15) * 128 + ((m2 * 64 + lg * 16) ^ swzW));
        __builtin_amdgcn_s_setprio(1);
#pragma unroll
        for (int chb = 0; chb < 4; ++chb)
          acc[qb][chb] = __builtin_amdgcn_mfma_f32_16x16x32_bf16(
              pa, vb[chb], acc[qb][chb], 0, 0, 0);
        __builtin_amdgcn_s_setprio(0);
      }
    }
    khp += (size_t)64 * CC;
    klp += (size_t)64 * CC;
    vp += 64;
    __builtin_amdgcn_s_barrier();  // bare rendezvous: L1-align the 4 waves
  }

  // z partials: sum over key-groups (lg) then atomic
#pragma unroll
  for (int qb = 0; qb < 2; ++qb) {
    zacc[qb] += __shfl_xor(zacc[qb], 16);
    zacc[qb] += __shfl_xor(zacc[qb], 32);
  }
  if (l < 16) {
    unsafeAtomicAdd(Z + (size_t)n * HW + qw0 + l, zacc[0]);
    unsafeAtomicAdd(Z + (size_t)n * HW + qw0 + 16 + l, zacc[1]);
  }
  // acc partials -> RES atomics (unnormalized; k_out divides by Z)
  float* resn = RES + ((size_t)n * HW + qw0) * CC;
#pragma unroll
  for (int qb = 0; qb < 2; ++qb)
#pragma unroll
    for (int r = 0; r < 4; ++r) {
      const int row = qb * 16 + lg * 4 + r;
#pragma unroll
      for (int chb = 0; chb < 4; ++chb)
        unsafeAtomicAdd(resn + (size_t)row * CC + chb * 16 + l15,
                        acc[qb][chb][r]);
    }
}

// ---------- kernel 4: out = x + wo @ (res/z reshaped) + bo
// res[n] flat [i][ch] == [c2][h2][w2]; conv mixes c2.  Row i = c2*64 + (j>>6).
__global__ __launch_bounds__(256) void k_out(const float* __restrict__ RES,
                                             const float* __restrict__ Z,
                                             const float* __restrict__ x,
                                             const float* __restrict__ wo,
                                             const float* __restrict__ bo,
                                             float* __restrict__ out) {
  const int n = blockIdx.x >> 5;
  const int j = ((blockIdx.x & 31) << 7) + (threadIdx.x & 127);  // h2*64+w2
  const int oh = threadIdx.x >> 7;  // o-half: 0 or 1
  const float* rn = RES + (size_t)n * HW * CC;
  const float* zb = Z + (size_t)n * HW;
  const int jh = j >> 6;
  float rcol[CC];
#pragma unroll
  for (int c2 = 0; c2 < CC; ++c2)
    rcol[c2] = rn[(size_t)c2 * HW + j] * (1.0f / zb[c2 * 64 + jh]);
  const size_t xb = (size_t)n * CC * HW;
  for (int o = oh * 32; o < oh * 32 + 32; ++o) {
    float sacc = bo[o];
#pragma unroll
    for (int c2 = 0; c2 < CC; ++c2)
      sacc = fmaf(wo[o * CC + c2], rcol[c2], sacc);
    out[xb + (size_t)o * HW + j] = x[xb + (size_t)o * HW + j] + sacc;
  }
}

extern "C" void kernel_launch(void* const* d_in, const int* in_sizes, int n_in,
                              void* d_out, int out_size, void* d_ws,
                              size_t ws_size, hipStream_t stream) {
  const float* x = (const float*)d_in[0];
  const float* gamma = (const float*)d_in[1];
  const float* beta = (const float*)d_in[2];
  const float* wq = (const float*)d_in[3];
  const float* bq = (const float*)d_in[4];
  const float* wk = (const float*)d_in[5];
  const float* bk = (const float*)d_in[6];
  const float* wv = (const float*)d_in[7];
  const float* bv = (const float*)d_in[8];
  const float* wo = (const float*)d_in[9];
  const float* bo = (const float*)d_in[10];
  float* out = (float*)d_out;

  char* ws = (char*)d_ws;
  // layout: [SACC 1KB][Z 128KB][RES 8MB][QH|QL|KH|KL|V 5x4MB]  (~28.5MB)
  float* SACC = (float*)ws;
  float* Z = (float*)(ws + 1024);
  float* RES = (float*)(ws + 1024 + (size_t)NBATCH * HW * 4);
  const size_t INIT_BYTES =
      1024 + (size_t)NBATCH * HW * 4 + (size_t)NBATCH * HW * CC * 4;
  const size_t ARR = (size_t)NBATCH * HW * CC;
  u16* QH = (u16*)(ws + INIT_BYTES);
  u16* QL = QH + ARR;
  u16* KH = QL + ARR;
  u16* KL = KH + ARR;
  u16* V = KL + ARR;

  hipMemsetAsync(ws, 0, INIT_BYTES, stream);  // zero SACC, Z, RES
  hipLaunchKernelGGL(k_stats1, dim3(512), dim3(256), 0, stream, x, SACC);
  hipLaunchKernelGGL(k_qkv, dim3(512), dim3(256), 0, stream, x, SACC, gamma,
                     beta, wq, bq, wk, bk, wv, bv, QH, QL, KH, KL, V);
  hipLaunchKernelGGL(k_attn, dim3(1024), dim3(256), 0, stream, QH, QL, KH, KL,
                     V, RES, Z);
  hipLaunchKernelGGL(k_out, dim3(256), dim3(256), 0, stream, RES, Z, x, wo, bo,
                     out);
}

// Round 6
// 232.089 us; speedup vs baseline: 2.1927x; 2.1927x over previous
//
#include <hip/hip_runtime.h>

// SelfAttnBlock: BN -> QKV 1x1conv -> full 4096x4096 attention (flash-style,
// never materialized) -> 1x1 conv -> residual.  MI355X gfx950.
//
// R6 = R5 resubmit (R5 never ran: GPU unavailable) + k_qkv scalar-W fix.
//  - R4 post-mortem: launch_bounds(256,4) -> VGPR 64 -> spills (FETCH/WRITE
//    +37MB, MfmaUtil 8%). Occupancy-via-registers is a dead end: live set
//    ~150+ regs. Root bottleneck = K/V load latency in front of MFMA with
//    only ~2 blocks/CU resident.
//  - Fix: async K/V staging via global_load_lds (no VGPR cost), double
//    buffered, SHARED by all 4 waves (each wave = 32 q-rows x all keys).
//    Schedule: stage(t+1) -> compute(t) -> vmcnt(0)+s_barrier (one
//    barrier/step; stage latency hides under ~600cyc compute).
//  - LDS 64KB: KH/KL/V 3x2x8KB dbuf + P 16KB -> 2 blocks/CU by design.
//    launch_bounds(256,2) -> VGPR cap 256, no spill (need ~180-210).
//  - Swizzle per rule#21: LDS linear dest + INVERSE-swizzled global src +
//    XOR-swizzled read (byte ^= (row&7)<<4); frag reads at b128 BW floor.
//    Invariant: LDS[row][cb] = global[row][cb ^ ((row&7)<<4)], both sides.
//  - SPLIT=2 (512 blocks = exactly 2/CU), halves atomic traffic vs R3.
//  - k_qkv: readfirstlane(w) -> weight reads provably wave-uniform -> SGPR
//    scalar loads instead of 3072 per-lane vector loads.
//  - Numerics identical to R2..R4 (absmax 0.015625 passing): QK bf16 hi/lo
//    (6 MFMAs), P/V single bf16, no-max softmax in exp2 domain, f32 atomics.

#define HW 4096
#define CC 64
#define NBATCH 8
#define SPLIT 2
#define TSTEPS 32  // 64-key steps per block (2048 keys)
// 0.125 * log2(e): fold attention scale + exp->exp2 conversion into Q
#define QSCALE 0.18033688011112042f

using f32x4 = __attribute__((ext_vector_type(4))) float;
using bf16x8 = __attribute__((ext_vector_type(8))) short;
using u32x2 = __attribute__((ext_vector_type(2))) unsigned int;
typedef unsigned short u16;
typedef unsigned int u32;

#if __has_builtin(__builtin_amdgcn_exp2f)
#define EXP2F(v) __builtin_amdgcn_exp2f(v)
#else
#define EXP2F(v) exp2f(v)
#endif

#define MFMA16(a, b, c) __builtin_amdgcn_mfma_f32_16x16x32_bf16(a, b, c, 0, 0, 0)
#define GLDS(gsrc, ldst)                                              \
  __builtin_amdgcn_global_load_lds(                                   \
      (const __attribute__((address_space(1))) void*)(gsrc),          \
      (__attribute__((address_space(3))) void*)(ldst), 16, 0, 0)

__device__ __forceinline__ u16 f2bf(float v) {  // RNE f32->bf16
  u32 u = __float_as_uint(v);
  return (u16)((u + 0x7fffu + ((u >> 16) & 1u)) >> 16);
}
__device__ __forceinline__ float bf2f(u16 h) {
  return __uint_as_float(((u32)h) << 16);
}
__device__ __forceinline__ u32 cvtpk_bf16(float lo, float hi) {  // RNE pack
  u32 r;
  asm("v_cvt_pk_bf16_f32 %0, %1, %2" : "=v"(r) : "v"(lo), "v"(hi));
  return r;
}

// ---------- kernel 1: BN partial sums (per (n,c) plane) -> atomics into SACC
__global__ __launch_bounds__(256) void k_stats1(const float* __restrict__ x,
                                                float* __restrict__ SACC) {
  const int n = blockIdx.x >> 6;
  const int c = blockIdx.x & 63;
  const int tid = threadIdx.x;
  const float* xp = x + ((size_t)n * CC + c) * HW;
  float s1 = 0.f, s2 = 0.f;
#pragma unroll
  for (int i = tid; i < HW; i += 256) {
    const float v = xp[i];
    s1 += v;
    s2 += v * v;
  }
#pragma unroll
  for (int m = 1; m <= 32; m <<= 1) {
    s1 += __shfl_xor(s1, m);
    s2 += __shfl_xor(s2, m);
  }
  __shared__ float r1[4], r2[4];
  const int w = tid >> 6;
  if ((tid & 63) == 0) { r1[w] = s1; r2[w] = s2; }
  __syncthreads();
  if (tid == 0) {
    unsafeAtomicAdd(SACC + c, r1[0] + r1[1] + r1[2] + r1[3]);
    unsafeAtomicAdd(SACC + CC + c, r2[0] + r2[1] + r2[2] + r2[3]);
  }
}

// ---------- kernel 2: fused BN-apply + Q/K/V 1x1 convs + bf16 hi/lo quantize
// outputs: QH/QL/KH/KL as [n][hw][c] bf16 ; V as [n][c][hw] bf16
__device__ __forceinline__ void mm16(const float* __restrict__ W,
                                     const float* __restrict__ B,
                                     const float* xcol, int o0, float scale,
                                     float* outv) {
#pragma unroll
  for (int oo = 0; oo < 16; ++oo) {
    const int o = o0 + oo;
    float a = B[o];  // o wave-uniform (readfirstlane'd) -> SGPR scalar load
#pragma unroll
    for (int c = 0; c < CC; ++c) a = fmaf(W[o * CC + c], xcol[c], a);
    outv[oo] = a * scale;
  }
}

__device__ __forceinline__ void split_store16(const float* v16, u16* dh, u16* dl) {
  u32 hi[8], lo[8];
#pragma unroll
  for (int e = 0; e < 8; ++e) {
    const u16 h0 = f2bf(v16[2 * e]), h1 = f2bf(v16[2 * e + 1]);
    const float l0 = v16[2 * e] - bf2f(h0);
    const float l1 = v16[2 * e + 1] - bf2f(h1);
    hi[e] = (u32)h0 | ((u32)h1 << 16);
    lo[e] = (u32)f2bf(l0) | ((u32)f2bf(l1) << 16);
  }
  ((uint4*)dh)[0] = *(const uint4*)&hi[0];
  ((uint4*)dh)[1] = *(const uint4*)&hi[4];
  ((uint4*)dl)[0] = *(const uint4*)&lo[0];
  ((uint4*)dl)[1] = *(const uint4*)&lo[4];
}

__global__ __launch_bounds__(256) void k_qkv(
    const float* __restrict__ x, const float* __restrict__ SACC,
    const float* __restrict__ gamma, const float* __restrict__ beta,
    const float* __restrict__ wq, const float* __restrict__ bq,
    const float* __restrict__ wk, const float* __restrict__ bk,
    const float* __restrict__ wv, const float* __restrict__ bv,
    u16* __restrict__ QH, u16* __restrict__ QL, u16* __restrict__ KH,
    u16* __restrict__ KL, u16* __restrict__ V) {
  const int n = blockIdx.x >> 6;
  const int i0 = (blockIdx.x & 63) << 6;
  __shared__ float xn[CC][64];
  __shared__ float sa[CC], sb[CC];
  const int tid = threadIdx.x;
  if (tid < CC) {  // BN a,b from accumulated stats (biased var, eps=1e-5)
    const float inv = 1.0f / (float)(NBATCH * HW);
    const float mean = SACC[tid] * inv;
    const float var = SACC[CC + tid] * inv - mean * mean;
    const float a = rsqrtf(var + 1e-5f) * gamma[tid];
    sa[tid] = a;
    sb[tid] = beta[tid] - mean * a;
  }
  __syncthreads();
  {
    const int p = tid & 63;
    const int c0 = (tid >> 6) << 4;
    const float* xp = x + (size_t)n * CC * HW + i0 + p;
#pragma unroll
    for (int cc = 0; cc < 16; ++cc) {
      const int c = c0 + cc;
      xn[c][p] = fmaf(xp[(size_t)c * HW], sa[c], sb[c]);
    }
  }
  __syncthreads();
  // force wave-uniformity so W/B reads compile to SGPR scalar loads
  const int w = __builtin_amdgcn_readfirstlane(tid >> 6);
  const int p = tid & 63;
  float xcol[CC];
#pragma unroll
  for (int c = 0; c < CC; ++c) xcol[c] = xn[c][p];

  const size_t row = (size_t)n * HW + i0 + p;
  float v16[16];
  mm16(wq, bq, xcol, w * 16, QSCALE, v16);
  split_store16(v16, QH + row * CC + w * 16, QL + row * CC + w * 16);
  mm16(wk, bk, xcol, w * 16, 1.0f, v16);
  split_store16(v16, KH + row * CC + w * 16, KL + row * CC + w * 16);
  mm16(wv, bv, xcol, w * 16, 1.0f, v16);
#pragma unroll
  for (int oo = 0; oo < 16; ++oo)
    V[((size_t)n * CC + w * 16 + oo) * HW + i0 + p] = f2bf(v16[oo]);
}

// ---------- kernel 3: flash attention partial; 4 waves x 32 q-rows, keys
// staged to LDS via global_load_lds (async, double-buffered, wave-shared).
__global__ __launch_bounds__(256, 2) void k_attn(
    const u16* __restrict__ QH, const u16* __restrict__ QL,
    const u16* __restrict__ KH, const u16* __restrict__ KL,
    const u16* __restrict__ V, float* __restrict__ RES,
    float* __restrict__ Z) {
  // bid&7 = n -> all 64 blocks of batch n on one XCD (K/V ~3MB < 4MB L2)
  const int bid = blockIdx.x;
  const int n = bid & 7;
  const int qt = (bid >> 3) & 31;
  const int s = bid >> 8;  // key-range split 0..1
  const int tid = threadIdx.x;
  const int w = tid >> 6;
  const int l = tid & 63;
  const int l15 = l & 15;
  const int lg = l >> 4;
  const int qw0 = qt * 128 + w * 32;  // this wave's first q-row
  const int key0 = s * (TSTEPS * 64);

  __shared__ alignas(16) u16 KHs[2][64][64];  // [buf][key][ch]   8KB each
  __shared__ alignas(16) u16 KLs[2][64][64];
  __shared__ alignas(16) u16 Vs[2][64][64];   // [buf][ch][key]
  __shared__ alignas(16) u16 P[4][32][64];    // per-wave private

  // ---- staging: 24 x 1KB lines/t-step; wave w stages lines w*6..w*6+5.
  // LDS linear; global src pre-swizzled so a (row&7)<<4 byte-XOR read works.
  const int lr8 = l >> 3;
  const u32 eoff = (u32)(((l & 7) * 8) ^ (lr8 << 3));  // u16 units
  const u16* sp[6];
  u16* d0[6];
  u16* d1[6];
  size_t stp[6];
#pragma unroll
  for (int c = 0; c < 6; ++c) {
    const int idx = w * 6 + c;
    const int tile = idx >> 3;
    const int j = idx & 7;
    const int lrow = j * 8 + lr8;
    if (tile == 0) {
      sp[c] = KH + ((size_t)n * HW + key0 + lrow) * CC + eoff;
      stp[c] = (size_t)64 * CC;
      d0[c] = &KHs[0][j * 8][0];
      d1[c] = &KHs[1][j * 8][0];
    } else if (tile == 1) {
      sp[c] = KL + ((size_t)n * HW + key0 + lrow) * CC + eoff;
      stp[c] = (size_t)64 * CC;
      d0[c] = &KLs[0][j * 8][0];
      d1[c] = &KLs[1][j * 8][0];
    } else {
      sp[c] = V + ((size_t)n * CC + lrow) * HW + key0 + eoff;
      stp[c] = 64;
      d0[c] = &Vs[0][j * 8][0];
      d1[c] = &Vs[1][j * 8][0];
    }
  }
  auto stage = [&](int bufsel) {
#pragma unroll
    for (int c = 0; c < 6; ++c) {
      u16* dst = bufsel ? d1[c] : d0[c];
      GLDS(sp[c], dst);
      sp[c] += stp[c];
    }
  };

  // resident Q frags: lane holds Q[qw0+qb*16+l15][m*32+lg*8 .. +8] (hi/lo)
  bf16x8 qh[2][2], ql[2][2];
  {
    const size_t qbase = ((size_t)n * HW + qw0 + l15) * CC + lg * 8;
#pragma unroll
    for (int qb = 0; qb < 2; ++qb)
#pragma unroll
      for (int m = 0; m < 2; ++m) {
        const size_t off = qbase + (size_t)qb * 16 * CC + m * 32;
        qh[qb][m] = *(const bf16x8*)(QH + off);
        ql[qb][m] = *(const bf16x8*)(QL + off);
      }
  }

  f32x4 acc[2][4];
#pragma unroll
  for (int qb = 0; qb < 2; ++qb)
#pragma unroll
    for (int chb = 0; chb < 4; ++chb)
      acc[qb][chb] = (f32x4){0.f, 0.f, 0.f, 0.f};
  float zacc[2] = {0.f, 0.f};

  stage(0);  // t=0 -> buf0
  asm volatile("s_waitcnt vmcnt(0)\n\ts_barrier" ::: "memory");

  const int swz = (l15 & 7) << 4;  // byte-XOR within 128B row
  char* const Pw = (char*)&P[w][0][0];

#pragma unroll 1
  for (int t = 0; t < TSTEPS; ++t) {
    const int buf = t & 1;
    if (t + 1 < TSTEPS) stage(buf ^ 1);  // async, lands before next barrier
    const char* khb = (const char*)&KHs[buf][0][0];
    const char* klb = (const char*)&KLs[buf][0][0];
    const char* vsb = (const char*)&Vs[buf][0][0];

    // ---- QK phase: S^T = K*Q, hi/lo correction (drop Kl*Ql)
    f32x4 sc[2][4];
#pragma unroll
    for (int kb = 0; kb < 4; ++kb) {
      const int rb = (kb * 16 + l15) * 128;
      const int c0 = (lg * 16) ^ swz;
      const int c1 = (64 + lg * 16) ^ swz;
      const bf16x8 kh0 = *(const bf16x8*)(khb + rb + c0);
      const bf16x8 kh1 = *(const bf16x8*)(khb + rb + c1);
      const bf16x8 kl0 = *(const bf16x8*)(klb + rb + c0);
      const bf16x8 kl1 = *(const bf16x8*)(klb + rb + c1);
      __builtin_amdgcn_s_setprio(1);
#pragma unroll
      for (int qb = 0; qb < 2; ++qb) {
        f32x4 s4 = {0.f, 0.f, 0.f, 0.f};
        s4 = MFMA16(kh0, qh[qb][0], s4);
        s4 = MFMA16(kh1, qh[qb][1], s4);
        s4 = MFMA16(kh0, ql[qb][0], s4);
        s4 = MFMA16(kh1, ql[qb][1], s4);
        s4 = MFMA16(kl0, qh[qb][0], s4);
        s4 = MFMA16(kl1, qh[qb][1], s4);
        sc[qb][kb] = s4;
      }
      __builtin_amdgcn_s_setprio(0);
    }
    // ---- softmax numerator + P store (private region, swizzled)
#pragma unroll
    for (int qb = 0; qb < 2; ++qb) {
      char* const prow = Pw + (qb * 16 + l15) * 128;
      float zs = 0.f;
#pragma unroll
      for (int kb = 0; kb < 4; ++kb) {
        const float p0 = EXP2F(sc[qb][kb][0]);
        const float p1 = EXP2F(sc[qb][kb][1]);
        const float p2 = EXP2F(sc[qb][kb][2]);
        const float p3 = EXP2F(sc[qb][kb][3]);
        zs += (p0 + p1) + (p2 + p3);
        const u32x2 pk = {cvtpk_bf16(p0, p1), cvtpk_bf16(p2, p3)};
        *(u32x2*)(prow + ((kb * 32 + lg * 8) ^ swz)) = pk;
      }
      zacc[qb] += zs;
    }
    // ---- PV phase (same-wave P read-back; V from LDS)
#pragma unroll
    for (int m2 = 0; m2 < 2; ++m2) {
      const int cc2 = (m2 * 64 + lg * 16) ^ swz;
      bf16x8 vb[4];
#pragma unroll
      for (int chb = 0; chb < 4; ++chb)
        vb[chb] = *(const bf16x8*)(vsb + (chb * 16 + l15) * 128 + cc2);
      __builtin_amdgcn_s_setprio(1);
#pragma unroll
      for (int qb = 0; qb < 2; ++qb) {
        const bf16x8 pa = *(const bf16x8*)(Pw + (qb * 16 + l15) * 128 + cc2);
#pragma unroll
        for (int chb = 0; chb < 4; ++chb)
          acc[qb][chb] = MFMA16(pa, vb[chb], acc[qb][chb]);
      }
      __builtin_amdgcn_s_setprio(0);
    }
    // barrier: wait staged loads (vmcnt) + own LDS ops; single sync/step
    asm volatile("s_waitcnt vmcnt(0) lgkmcnt(0)\n\ts_barrier" ::: "memory");
  }

  // z partials: sum over key-groups (lg) then atomic
#pragma unroll
  for (int qb = 0; qb < 2; ++qb) {
    zacc[qb] += __shfl_xor(zacc[qb], 16);
    zacc[qb] += __shfl_xor(zacc[qb], 32);
  }
  if (l < 16) {
    unsafeAtomicAdd(Z + (size_t)n * HW + qw0 + l, zacc[0]);
    unsafeAtomicAdd(Z + (size_t)n * HW + qw0 + 16 + l, zacc[1]);
  }
  // acc partials -> RES atomics (unnormalized; k_out divides by Z)
  float* resn = RES + ((size_t)n * HW + qw0) * CC;
#pragma unroll
  for (int qb = 0; qb < 2; ++qb)
#pragma unroll
    for (int r = 0; r < 4; ++r) {
      const int row = qb * 16 + lg * 4 + r;
#pragma unroll
      for (int chb = 0; chb < 4; ++chb)
        unsafeAtomicAdd(resn + (size_t)row * CC + chb * 16 + l15,
                        acc[qb][chb][r]);
    }
}

// ---------- kernel 4: out = x + wo @ (res/z reshaped) + bo
// res[n] flat [i][ch] == [c2][h2][w2]; conv mixes c2.  Row i = c2*64 + (j>>6).
__global__ __launch_bounds__(256) void k_out(const float* __restrict__ RES,
                                             const float* __restrict__ Z,
                                             const float* __restrict__ x,
                                             const float* __restrict__ wo,
                                             const float* __restrict__ bo,
                                             float* __restrict__ out) {
  const int n = blockIdx.x >> 6;
  const int j = ((blockIdx.x & 63) << 6) + (threadIdx.x & 63);  // h2*64+w2
  const int oq = __builtin_amdgcn_readfirstlane(threadIdx.x >> 6);
  const float* rn = RES + (size_t)n * HW * CC;
  const float* zb = Z + (size_t)n * HW;
  const int jh = j >> 6;
  float rcol[CC];
#pragma unroll
  for (int c2 = 0; c2 < CC; ++c2)
    rcol[c2] = rn[(size_t)c2 * HW + j] * (1.0f / zb[c2 * 64 + jh]);
  const size_t xb = (size_t)n * CC * HW;
  for (int o = oq * 16; o < oq * 16 + 16; ++o) {
    float sacc = bo[o];
#pragma unroll
    for (int c2 = 0; c2 < CC; ++c2)
      sacc = fmaf(wo[o * CC + c2], rcol[c2], sacc);
    out[xb + (size_t)o * HW + j] = x[xb + (size_t)o * HW + j] + sacc;
  }
}

extern "C" void kernel_launch(void* const* d_in, const int* in_sizes, int n_in,
                              void* d_out, int out_size, void* d_ws,
                              size_t ws_size, hipStream_t stream) {
  const float* x = (const float*)d_in[0];
  const float* gamma = (const float*)d_in[1];
  const float* beta = (const float*)d_in[2];
  const float* wq = (const float*)d_in[3];
  const float* bq = (const float*)d_in[4];
  const float* wk = (const float*)d_in[5];
  const float* bk = (const float*)d_in[6];
  const float* wv = (const float*)d_in[7];
  const float* bv = (const float*)d_in[8];
  const float* wo = (const float*)d_in[9];
  const float* bo = (const float*)d_in[10];
  float* out = (float*)d_out;

  char* ws = (char*)d_ws;
  // layout: [SACC 1KB][Z 128KB][RES 8MB][QH|QL|KH|KL|V 5x4MB]  (~28.5MB)
  float* SACC = (float*)ws;
  float* Z = (float*)(ws + 1024);
  float* RES = (float*)(ws + 1024 + (size_t)NBATCH * HW * 4);
  const size_t INIT_BYTES =
      1024 + (size_t)NBATCH * HW * 4 + (size_t)NBATCH * HW * CC * 4;
  const size_t ARR = (size_t)NBATCH * HW * CC;
  u16* QH = (u16*)(ws + INIT_BYTES);
  u16* QL = QH + ARR;
  u16* KH = QL + ARR;
  u16* KL = KH + ARR;
  u16* V = KL + ARR;

  hipMemsetAsync(ws, 0, INIT_BYTES, stream);  // zero SACC, Z, RES
  hipLaunchKernelGGL(k_stats1, dim3(512), dim3(256), 0, stream, x, SACC);
  hipLaunchKernelGGL(k_qkv, dim3(512), dim3(256), 0, stream, x, SACC, gamma,
                     beta, wq, bq, wk, bk, wv, bv, QH, QL, KH, KL, V);
  hipLaunchKernelGGL(k_attn, dim3(512), dim3(256), 0, stream, QH, QL, KH, KL,
                     V, RES, Z);
  hipLaunchKernelGGL(k_out, dim3(512), dim3(256), 0, stream, RES, Z, x, wo, bo,
                     out);
}